// Round 3
// baseline (718.652 us; speedup 1.0000x reference)
//
#include <hip/hip_runtime.h>
#include <math.h>

#define K_DIM 512
#define N_DIM 512
#define W_ELEMS (K_DIM * N_DIM)  // 262144 = 2^18
#define NLEAF 2048               // numpy pairwise leaves of 128
#define BM 64
#define BN 64
#define BK 64

// ---------------------------------------------------------------------------
// ws[0] = mu = np.mean(w), ws[1] = gamma = np.mean(|w|), in BIT-EXACT numpy
// float32 pairwise order: perfect binary tree over 2048 leaves of 128, each
// leaf uses numpy's 8-accumulator pattern with combine
// ((r0+r1)+(r2+r3))+((r4+r5)+(r6+r7)); final scale by 2^-18 (exact).
// VALIDATED by round-2 segment experiment (seg-1 rows flip-free).
// ---------------------------------------------------------------------------
__global__ void means_kernel(const float* __restrict__ w, float* __restrict__ ws) {
  __shared__ float bufS[4096];
  __shared__ float bufA[4096];
  const int t = threadIdx.x;  // 256 threads, 1 block
  for (int leaf = t * 8; leaf < t * 8 + 8; ++leaf) {
    const float* p = w + leaf * 128;
    float rs[8], ra[8];
    #pragma unroll
    for (int j = 0; j < 8; ++j) { const float v = p[j]; rs[j] = v; ra[j] = fabsf(v); }
    for (int i = 8; i < 128; i += 8) {
      #pragma unroll
      for (int j = 0; j < 8; ++j) { const float v = p[i + j]; rs[j] += v; ra[j] += fabsf(v); }
    }
    bufS[leaf] = ((rs[0] + rs[1]) + (rs[2] + rs[3])) + ((rs[4] + rs[5]) + (rs[6] + rs[7]));
    bufA[leaf] = ((ra[0] + ra[1]) + (ra[2] + ra[3])) + ((ra[4] + ra[5]) + (ra[6] + ra[7]));
  }
  __syncthreads();
  int src = 0, n = NLEAF;
  while (n > 1) {
    const int dst = src + n;
    n >>= 1;
    for (int i = t; i < n; i += 256) {
      bufS[dst + i] = bufS[src + 2 * i] + bufS[src + 2 * i + 1];
      bufA[dst + i] = bufA[src + 2 * i] + bufA[src + 2 * i + 1];
    }
    __syncthreads();
    src = dst;
  }
  if (t == 0) {
    ws[0] = bufS[src] * (1.0f / 262144.0f);
    ws[1] = bufA[src] * (1.0f / 262144.0f);
  }
}

// ---------------------------------------------------------------------------
// fp32 GEMM, pure sequential-k fmaf chain per output (the validated seg-1
// numerics), fused faithful-fp32 STE weight DAG + fp32 quantizer epilogue.
// 64x64 tile, 256 threads, 4x4 micro-tile. Tiling does NOT perturb the
// per-output accumulation order (k strictly ascending 0..511).
// ---------------------------------------------------------------------------
__global__ __launch_bounds__(256) void gemm_kernel(
    const float* __restrict__ x, const float* __restrict__ w,
    const float* __restrict__ bias, const float* __restrict__ ws,
    float* __restrict__ out) {
  __shared__ float As[BK][BM + 4];  // [k][m], +4 keeps rows 16B-aligned, breaks conflicts
  __shared__ float Bs[BK][BN];      // [k][n] = effective weight

  const float mu = ws[0];
  const float gamma = ws[1];
  const int tx = threadIdx.x & 15;  // col group
  const int ty = threadIdx.x >> 4;  // row group
  const int rowBase = blockIdx.x * BM;
  const int colBase = blockIdx.y * BN;

  float acc[16];
  #pragma unroll
  for (int i = 0; i < 16; ++i) acc[i] = 0.0f;

  for (int kc = 0; kc < K_DIM / BK; ++kc) {  // 8 chunks, ascending k
    // stage A: x tile transposed to [k][m]
    #pragma unroll
    for (int p = 0; p < 4; ++p) {
      const int r = p * 16 + ty;
      const int k4 = tx * 4;
      const float4 v = *(const float4*)&x[(size_t)(rowBase + r) * K_DIM + kc * BK + k4];
      As[k4 + 0][r] = v.x;
      As[k4 + 1][r] = v.y;
      As[k4 + 2][r] = v.z;
      As[k4 + 3][r] = v.w;
    }
    // stage B: effective weight via the faithful fp32 STE DAG:
    // eff = fl(fl(w + fl(sign(fl(w-mu)) - w)) * gamma)
    #pragma unroll
    for (int p = 0; p < 4; ++p) {
      const int kk = p * 16 + ty;
      const int j4 = tx * 4;
      const float4 v = *(const float4*)&w[(size_t)(kc * BK + kk) * N_DIM + colBase + j4];
      float4 e;
      const float* vi = &v.x;
      float* ei = &e.x;
      #pragma unroll
      for (int c = 0; c < 4; ++c) {
        const float wv = vi[c];
        const float wc = wv - mu;
        const float bin = (wc > 0.0f) ? 1.0f : ((wc < 0.0f) ? -1.0f : 0.0f);
        const float ste = wv + (bin - wv);   // NOT exactly bin — keep fp32 DAG
        ei[c] = ste * gamma;
      }
      *(float4*)&Bs[kk][j4] = e;
    }
    __syncthreads();

    #pragma unroll 8
    for (int k = 0; k < BK; ++k) {
      const float4 a = *(const float4*)&As[k][ty * 4];
      const float4 b = *(const float4*)&Bs[k][tx * 4];
      const float* ai = &a.x; const float* bi = &b.x;
      #pragma unroll
      for (int i = 0; i < 4; ++i)
        #pragma unroll
        for (int j = 0; j < 4; ++j)
          acc[i * 4 + j] = fmaf(ai[i], bi[j], acc[i * 4 + j]);
    }
    __syncthreads();
  }

  // faithful fp32 epilogue: yb=y+bias; c=clip; t=c*7; r=rintf(t) [RNE]; q=r/7;
  // out = yb + (q - yb)   (the STE value path)
  #pragma unroll
  for (int i = 0; i < 4; ++i) {
    float4 o;
    float* op = &o.x;
    #pragma unroll
    for (int j = 0; j < 4; ++j) {
      const float yb = acc[i * 4 + j] + bias[colBase + tx * 4 + j];
      const float cl = fminf(fmaxf(yb, -1.0f), 1.0f);
      const float t7 = cl * 7.0f;
      const float rr = rintf(t7);
      const float q = rr / 7.0f;
      op[j] = yb + (q - yb);
    }
    *(float4*)&out[(size_t)(rowBase + ty * 4 + i) * N_DIM + colBase + tx * 4] = o;
  }
}

extern "C" void kernel_launch(void* const* d_in, const int* in_sizes, int n_in,
                              void* d_out, int out_size, void* d_ws, size_t ws_size,
                              hipStream_t stream) {
  const float* x = (const float*)d_in[0];
  const float* w = (const float*)d_in[1];
  const float* bias = (const float*)d_in[2];
  float* out = (float*)d_out;
  float* ws = (float*)d_ws;  // 8 bytes used

  const int M = in_sizes[0] / K_DIM;  // 65536 rows

  means_kernel<<<1, 256, 0, stream>>>(w, ws);
  gemm_kernel<<<dim3(M / BM, N_DIM / BN), 256, 0, stream>>>(x, w, bias, ws, out);
}

// Round 4
// 585.633 us; speedup vs baseline: 1.2271x; 1.2271x over previous
//
#include <hip/hip_runtime.h>
#include <math.h>

#define K_DIM 512
#define N_DIM 512
#define NLEAF 2048   // numpy pairwise leaves of 128 over 2^18 elements
#define BM 128
#define BN 128
#define BK 32

// ws float layout: [0]=mu, [1]=gamma, [16..16+2047]=leaf sums, [2064..4111]=leaf abs-sums
#define WS_LEAFS 16
#define WS_LEAFA (16 + NLEAF)

// ---------------------------------------------------------------------------
// NUMERICS CONTRACT (validated round 3, absmax==0.0 — DO NOT CHANGE):
//  mu/gamma: numpy fp32 pairwise tree — 2048 leaves of 128 elems, each leaf
//    via 8-accumulator pattern + combine ((r0+r1)+(r2+r3))+((r4+r5)+(r6+r7)),
//    then perfect binary tree (left+right), scale by 2^-18.
//  eff_w = fl(fl(w + fl(sign(fl(w-mu)) - w)) * gamma)
//  y: per-output single fp32 accumulator, fmaf chain, k STRICTLY ascending.
//  epilogue: yb=y+bias; cl=clip; rr=rintf(cl*7); q=rr/7; out=yb+(q-yb).
// ---------------------------------------------------------------------------

// Leaf sums: one thread per leaf, sequential 8-acc pattern (bit-exact order).
__global__ void leaf_kernel(const float* __restrict__ w, float* __restrict__ ws) {
  const int leaf = blockIdx.x * blockDim.x + threadIdx.x;  // 2048 total
  const float* p = w + leaf * 128;
  float rs[8], ra[8];
  #pragma unroll
  for (int j = 0; j < 8; ++j) { const float v = p[j]; rs[j] = v; ra[j] = fabsf(v); }
  for (int i = 8; i < 128; i += 8) {
    #pragma unroll
    for (int j = 0; j < 8; ++j) { const float v = p[i + j]; rs[j] += v; ra[j] += fabsf(v); }
  }
  ws[WS_LEAFS + leaf] = ((rs[0] + rs[1]) + (rs[2] + rs[3])) + ((rs[4] + rs[5]) + (rs[6] + rs[7]));
  ws[WS_LEAFA + leaf] = ((ra[0] + ra[1]) + (ra[2] + ra[3])) + ((ra[4] + ra[5]) + (ra[6] + ra[7]));
}

// Binary-tree combine of the 2048 leaf partials, exact numpy pairing.
__global__ void tree_kernel(float* __restrict__ ws) {
  __shared__ float bufS[4096];
  __shared__ float bufA[4096];
  const int t = threadIdx.x;  // 256 threads, 1 block
  for (int i = t; i < NLEAF; i += 256) {
    bufS[i] = ws[WS_LEAFS + i];
    bufA[i] = ws[WS_LEAFA + i];
  }
  __syncthreads();
  int src = 0, n = NLEAF;
  while (n > 1) {
    const int dst = src + n;
    n >>= 1;
    for (int i = t; i < n; i += 256) {
      bufS[dst + i] = bufS[src + 2 * i] + bufS[src + 2 * i + 1];
      bufA[dst + i] = bufA[src + 2 * i] + bufA[src + 2 * i + 1];
    }
    __syncthreads();
    src = dst;
  }
  if (t == 0) {
    ws[0] = bufS[src] * (1.0f / 262144.0f);  // exact pow2 scale == np divide
    ws[1] = bufA[src] * (1.0f / 262144.0f);
  }
}

// 128x128 block tile, 256 threads, 8x8 micro-tile (2x2 quadrants of 4x4),
// BK=32, A staged untransposed [m][k] (k-contiguous b128 reads, 4-k batches).
__global__ __launch_bounds__(256, 4) void gemm_kernel(
    const float* __restrict__ x, const float* __restrict__ w,
    const float* __restrict__ bias, const float* __restrict__ ws,
    float* __restrict__ out) {
  __shared__ float As[BM][BK + 4];  // [m][k], stride 36 dwords (16B-aligned rows)
  __shared__ float Bs[BK][BN + 4];  // [k][n], stride 132 dwords

  const float mu = ws[0];
  const float gamma = ws[1];
  const int t = threadIdx.x;
  const int tx = t & 15;   // col group: cols {tx*4..+3} and {64+tx*4..+3}
  const int ty = t >> 4;   // row group: rows {ty*4..+3} and {64+ty*4..+3}
  const int rowBase = blockIdx.x * BM;
  const int colBase = blockIdx.y * BN;

  float acc[2][2][4][4];
  #pragma unroll
  for (int h = 0; h < 2; ++h)
    #pragma unroll
    for (int g = 0; g < 2; ++g)
      #pragma unroll
      for (int i = 0; i < 4; ++i)
        #pragma unroll
        for (int j = 0; j < 4; ++j) acc[h][g][i][j] = 0.0f;

  for (int kc = 0; kc < K_DIM; kc += BK) {  // 16 chunks, ascending k
    // stage A: 128 rows x 32 k, coalesced (8 lanes * 16B = 128B per row)
    #pragma unroll
    for (int p = 0; p < 4; ++p) {
      const int r = (t >> 3) + 32 * p;
      const int k4 = (t & 7) * 4;
      const float4 v = *(const float4*)&x[(size_t)(rowBase + r) * K_DIM + kc + k4];
      *(float4*)&As[r][k4] = v;
    }
    // stage B: 32 k x 128 n, fused faithful-fp32 STE weight DAG
    #pragma unroll
    for (int p = 0; p < 4; ++p) {
      const int kk = (t >> 5) + 8 * p;
      const int n4 = (t & 31) * 4;
      const float4 v = *(const float4*)&w[(size_t)(kc + kk) * N_DIM + colBase + n4];
      float4 e;
      const float* vi = &v.x;
      float* ei = &e.x;
      #pragma unroll
      for (int c = 0; c < 4; ++c) {
        const float wv = vi[c];
        const float wc = wv - mu;
        const float bin = (wc > 0.0f) ? 1.0f : ((wc < 0.0f) ? -1.0f : 0.0f);
        const float ste = wv + (bin - wv);   // keep exact fp32 DAG
        ei[c] = ste * gamma;
      }
      *(float4*)&Bs[kk][n4] = e;
    }
    __syncthreads();

    #pragma unroll
    for (int kg = 0; kg < 8; ++kg) {  // 8 groups of 4 k
      float4 a0[4], a1[4];
      #pragma unroll
      for (int i = 0; i < 4; ++i) {
        a0[i] = *(const float4*)&As[ty * 4 + i][kg * 4];
        a1[i] = *(const float4*)&As[64 + ty * 4 + i][kg * 4];
      }
      #pragma unroll
      for (int kk = 0; kk < 4; ++kk) {  // k ascending within group
        const float4 b0 = *(const float4*)&Bs[kg * 4 + kk][tx * 4];
        const float4 b1 = *(const float4*)&Bs[kg * 4 + kk][64 + tx * 4];
        const float* b0p = &b0.x;
        const float* b1p = &b1.x;
        #pragma unroll
        for (int i = 0; i < 4; ++i) {
          const float av0 = (&a0[i].x)[kk];
          const float av1 = (&a1[i].x)[kk];
          #pragma unroll
          for (int j = 0; j < 4; ++j) {
            acc[0][0][i][j] = fmaf(av0, b0p[j], acc[0][0][i][j]);
            acc[0][1][i][j] = fmaf(av0, b1p[j], acc[0][1][i][j]);
            acc[1][0][i][j] = fmaf(av1, b0p[j], acc[1][0][i][j]);
            acc[1][1][i][j] = fmaf(av1, b1p[j], acc[1][1][i][j]);
          }
        }
      }
    }
    __syncthreads();
  }

  // faithful fp32 epilogue (unchanged from validated round 3)
  #pragma unroll
  for (int h = 0; h < 2; ++h)
    #pragma unroll
    for (int i = 0; i < 4; ++i) {
      const size_t row = (size_t)(rowBase + h * 64 + ty * 4 + i);
      #pragma unroll
      for (int g = 0; g < 2; ++g) {
        const int col = colBase + g * 64 + tx * 4;
        float4 o;
        float* op = &o.x;
        #pragma unroll
        for (int j = 0; j < 4; ++j) {
          const float yb = acc[h][g][i][j] + bias[col + j];
          const float cl = fminf(fmaxf(yb, -1.0f), 1.0f);
          const float t7 = cl * 7.0f;
          const float rr = rintf(t7);
          const float q = rr / 7.0f;
          op[j] = yb + (q - yb);
        }
        *(float4*)&out[row * N_DIM + col] = o;
      }
    }
}

extern "C" void kernel_launch(void* const* d_in, const int* in_sizes, int n_in,
                              void* d_out, int out_size, void* d_ws, size_t ws_size,
                              hipStream_t stream) {
  const float* x = (const float*)d_in[0];
  const float* w = (const float*)d_in[1];
  const float* bias = (const float*)d_in[2];
  float* out = (float*)d_out;
  float* ws = (float*)d_ws;  // uses 16448 bytes

  const int M = in_sizes[0] / K_DIM;  // 65536 rows

  leaf_kernel<<<NLEAF / 256, 256, 0, stream>>>(w, ws);
  tree_kernel<<<1, 256, 0, stream>>>(ws);
  gemm_kernel<<<dim3(M / BM, N_DIM / BN), 256, 0, stream>>>(x, w, bias, ws, out);
}